// Round 14
// baseline (141.965 us; speedup 1.0000x reference)
//
#include <hip/hip_runtime.h>
#include <hip/hip_cooperative_groups.h>

namespace cg = cooperative_groups;

#define HW   4096      // 64*64
#define NC   256
#define NTB  24        // 3 tensors * 8 batches
#define TOPK 2048      // max(1, int(0.5 * 4096))

typedef float vf4 __attribute__((ext_vector_type(4)));

#define CHB  8
#define BPR  (NC / CHB)            // 32 blocks per row
#define K2B  (NTB * BPR)           // 768 blocks total
#define VPT  (CHB * HW / 4 / 256)  // 32 vf4 per thread (apply)
#define NCHAIN (NTB * HW)          // 98304 importance chains

// ===========================================================================
// Select+apply body (R13-proven, absmax 0): distributed select u[16]/thread
// (no spill), binary search on uint bits w/ ping-pong LDS cross-wave sums,
// stable ties via wave scan + cross-wave prefix, 4096-bit mask in LDS,
// then stream 8 channels: cached loads, bit-select, nontemporal stores.
// ===========================================================================
__device__ __forceinline__ void selapply_body(const float* __restrict__ i0,
                                              const float* __restrict__ i1,
                                              const float* __restrict__ i2,
                                              const float* __restrict__ imp,
                                              vf4* __restrict__ out,
                                              int blk, int tid,
                                              unsigned short* mhalf,
                                              unsigned* smn, unsigned* smx,
                                              int (*scnt)[4], int* sgt, int* seq_) {
  const int row  = blk >> 5;                   // 0..23 (t*8+b)
  const int cb   = blk & 31;                   // 8-channel chunk within row
  const int lane = tid & 63;
  const int wv   = tid >> 6;

  unsigned u[16];
  {
    const vf4* p = reinterpret_cast<const vf4*>(imp + (size_t)row * HW) + tid * 4;
#pragma unroll
    for (int j = 0; j < 4; ++j) {
      vf4 v = p[j];
      u[4 * j + 0] = __float_as_uint(v.x);
      u[4 * j + 1] = __float_as_uint(v.y);
      u[4 * j + 2] = __float_as_uint(v.z);
      u[4 * j + 3] = __float_as_uint(v.w);
    }
  }

  unsigned mx = 0u, mn = 0xFFFFFFFFu;
#pragma unroll
  for (int j = 0; j < 16; ++j) {
    mx = (u[j] > mx) ? u[j] : mx;
    mn = (u[j] < mn) ? u[j] : mn;
  }
#pragma unroll
  for (int off = 32; off > 0; off >>= 1) {
    unsigned ox = (unsigned)__shfl_xor((int)mx, off, 64);
    unsigned on = (unsigned)__shfl_xor((int)mn, off, 64);
    mx = (ox > mx) ? ox : mx;
    mn = (on < mn) ? on : mn;
  }
  if (lane == 0) { smn[wv] = mn; smx[wv] = mx; }
  __syncthreads();
#pragma unroll
  for (int w = 0; w < 4; ++w) {
    mn = (smn[w] < mn) ? smn[w] : mn;
    mx = (smx[w] > mx) ? smx[w] : mx;
  }

  unsigned lo = mn, hi = mx + 1u;              // cnt_ge(lo)>=K, cnt_ge(hi)<K
  int pp = 0;
  while (hi - lo > 1u) {
    unsigned mid = lo + ((hi - lo) >> 1);
    int c = 0;
#pragma unroll
    for (int j = 0; j < 16; ++j) c += (u[j] >= mid);
#pragma unroll
    for (int off = 32; off > 0; off >>= 1) c += __shfl_xor(c, off, 64);
    if (lane == 0) scnt[pp][wv] = c;
    __syncthreads();                           // ping-pong: 1 barrier/iter
    c = scnt[pp][0] + scnt[pp][1] + scnt[pp][2] + scnt[pp][3];  // uniform
    pp ^= 1;
    if (c >= TOPK) lo = mid; else hi = mid;
  }
  const unsigned thr = lo;

  int eq = 0, gt = 0;
#pragma unroll
  for (int j = 0; j < 16; ++j) {
    eq += (u[j] == thr);
    gt += (u[j] > thr);
  }
  int g = gt;
#pragma unroll
  for (int off = 32; off > 0; off >>= 1) g += __shfl_xor(g, off, 64);
  int incl = eq;
#pragma unroll
  for (int off = 1; off < 64; off <<= 1) {
    int n = __shfl_up(incl, off, 64);
    if (lane >= off) incl += n;
  }
  if (lane == 0) sgt[wv] = g;
  if (lane == 63) seq_[wv] = incl;
  __syncthreads();
  const int g_tot = sgt[0] + sgt[1] + sgt[2] + sgt[3];
  int eqbase = 0;
#pragma unroll
  for (int w = 0; w < 4; ++w) eqbase += (w < wv) ? seq_[w] : 0;
  int r = eqbase + incl - eq;                  // exclusive prefix, this thread
  const int needed = TOPK - g_tot;

  unsigned bits = 0u;
#pragma unroll
  for (int s = 0; s < 16; ++s) {
    unsigned x = u[s];
    int e = (x == thr);
    unsigned keep = (x > thr || (e && r < needed)) ? 1u : 0u;
    bits |= keep << s;
    r += e;
  }
  mhalf[tid] = (unsigned short)bits;
  __syncthreads();

  const int t = row >> 3;
  const vf4* src = (t == 0 ? (const vf4*)i0 : (t == 1 ? (const vf4*)i1 : (const vf4*)i2));
  const size_t src_base = ((size_t)(row & 7) * NC + (size_t)cb * CHB) * (HW / 4);
  vf4* obase = out + (size_t)row * NC * (HW / 4) + (size_t)cb * CHB * (HW / 4);
#pragma unroll
  for (int it = 0; it < VPT / 4; ++it) {
    int jj[4];
    vf4 a[4];
    unsigned nib[4];
#pragma unroll
    for (int q = 0; q < 4; ++q) {
      int j = tid + (it * 4 + q) * 256;        // 0..8191 vf4 within chunk
      jj[q] = j;
      a[q] = src[src_base + j];                // cached read (L3-resident)
      int h4 = j & 1023;                       // vf4 col within row
      nib[q] = ((unsigned)mhalf[h4 >> 2] >> ((h4 & 3) * 4)) & 15u;
    }
#pragma unroll
    for (int q = 0; q < 4; ++q) {
      vf4 rr;
      rr.x = (nib[q] & 1u) ? a[q].x : 0.f;
      rr.y = (nib[q] & 2u) ? a[q].y : 0.f;
      rr.z = (nib[q] & 4u) ? a[q].z : 0.f;
      rr.w = (nib[q] & 8u) ? a[q].w : 0.f;
      __builtin_nontemporal_store(rr, &obase[jj[q]]);
    }
  }
}

// ===========================================================================
// Single cooperative kernel: phase A (every block works: gid<98304 runs one
// R5 scalar chain -> 1536 active waves, same geometry as the standalone K1)
// -> grid.sync (R6-proven correct across XCDs; near-zero spin since all
// blocks arrive together) -> R13 select+apply body.
// ===========================================================================
__global__ __launch_bounds__(256) void k_all(const float* __restrict__ i0,
                                             const float* __restrict__ i1,
                                             const float* __restrict__ i2,
                                             float* __restrict__ imp,
                                             vf4* __restrict__ out) {
  __shared__ unsigned short mhalf[256];
  __shared__ unsigned smn[4], smx[4];
  __shared__ int scnt[2][4];
  __shared__ int sgt[4], seq_[4];

  cg::grid_group grid = cg::this_grid();
  const int blk = blockIdx.x;
  const int tid = threadIdx.x;
  const int gid = blk * 256 + tid;

  // ---- phase A: imp = mean_c |x|, sequential chain (bitwise == np) -------
  if (gid < NCHAIN) {
    int hw = gid & (HW - 1);
    int tb = gid >> 12;                        // 0..23
    int t  = tb >> 3;
    const float* base = (t == 0 ? i0 : (t == 1 ? i1 : i2));
    const float* p = base + (size_t)(tb & 7) * NC * HW + hw;
    float s = 0.f;
#pragma unroll 32
    for (int c = 0; c < NC; ++c) s += fabsf(p[c * HW]);  // program order
    imp[gid] = s * (1.0f / 256.0f);            // exact pow2 == /256.0
  }

  grid.sync();

  // ---- phase B+C ----------------------------------------------------------
  selapply_body(i0, i1, i2, imp, out, blk, tid, mhalf, smn, smx, scnt, sgt, seq_);
}

// ===========================================================================
// Fallback: exact R13 two-kernel path (63.3 us proven).
// ===========================================================================
__global__ __launch_bounds__(256) void k_imp(const float* __restrict__ i0,
                                             const float* __restrict__ i1,
                                             const float* __restrict__ i2,
                                             float* __restrict__ imp) {
  int tid = blockIdx.x * 256 + threadIdx.x;
  int hw  = tid & (HW - 1);
  int tb  = tid >> 12;
  int t   = tb >> 3;
  const float* base = (t == 0 ? i0 : (t == 1 ? i1 : i2));
  const float* p = base + (size_t)(tb & 7) * NC * HW + hw;
  float s = 0.f;
#pragma unroll 32
  for (int c = 0; c < NC; ++c) s += fabsf(p[c * HW]);
  imp[tid] = s * (1.0f / 256.0f);
}

__global__ __launch_bounds__(256) void k_selapply(const float* __restrict__ i0,
                                                  const float* __restrict__ i1,
                                                  const float* __restrict__ i2,
                                                  const float* __restrict__ imp,
                                                  vf4* __restrict__ out) {
  __shared__ unsigned short mhalf[256];
  __shared__ unsigned smn[4], smx[4];
  __shared__ int scnt[2][4];
  __shared__ int sgt[4], seq_[4];
  selapply_body(i0, i1, i2, imp, out, blockIdx.x, threadIdx.x,
                mhalf, smn, smx, scnt, sgt, seq_);
}

extern "C" void kernel_launch(void* const* d_in, const int* in_sizes, int n_in,
                              void* d_out, int out_size, void* d_ws, size_t ws_size,
                              hipStream_t stream) {
  const float* i0 = (const float*)d_in[0];
  const float* i1 = (const float*)d_in[1];
  const float* i2 = (const float*)d_in[2];
  float* imp = (float*)d_ws;   // 384 KB scratch (imp only; mask stays on-chip)
  vf4* out = (vf4*)d_out;

  void* args[] = {(void*)&i0, (void*)&i1, (void*)&i2, (void*)&imp, (void*)&out};
  hipError_t err = hipLaunchCooperativeKernel((const void*)k_all,
                                              dim3(K2B), dim3(256),
                                              args, 0, stream);
  if (err != hipSuccess) {
    k_imp<<<384, 256, 0, stream>>>(i0, i1, i2, imp);
    k_selapply<<<K2B, 256, 0, stream>>>(i0, i1, i2, imp, out);
  }
}

// Round 15
// 63.233 us; speedup vs baseline: 2.2451x; 2.2451x over previous
//
#include <hip/hip_runtime.h>

#define HW   4096      // 64*64
#define NC   256
#define NTB  24        // 3 tensors * 8 batches
#define TOPK 2048      // max(1, int(0.5 * 4096))

typedef float vf4 __attribute__((ext_vector_type(4)));

#define CHB  8
#define BPR  (NC / CHB)            // 32 blocks per row
#define K2B  (NTB * BPR)           // 768 blocks total
#define VPT  (CHB * HW / 4 / 256)  // 32 vf4 per thread (apply)

// ---------------------------------------------------------------------------
// K1 (pass A, R5/R13-proven): imp[tb][hw] = (sum_{c seq} |x|)/256, bitwise ==
// np reduce order. Scalar chain/thread, 384 blocks x 256, unroll-32.
// ---------------------------------------------------------------------------
__global__ __launch_bounds__(256) void k_imp(const float* __restrict__ i0,
                                             const float* __restrict__ i1,
                                             const float* __restrict__ i2,
                                             float* __restrict__ imp) {
  int tid = blockIdx.x * 256 + threadIdx.x;   // 0 .. 98303
  int hw  = tid & (HW - 1);
  int tb  = tid >> 12;                        // 0 .. 23
  int t   = tb >> 3;
  const float* base = (t == 0 ? i0 : (t == 1 ? i1 : i2));
  const float* p = base + (size_t)(tb & 7) * NC * HW + hw;
  float s = 0.f;
#pragma unroll 32
  for (int c = 0; c < NC; ++c) s += fabsf(p[c * HW]);  // program order per chain
  imp[tid] = s * (1.0f / 256.0f);             // exact pow2 == /256.0
}

// ---------------------------------------------------------------------------
// K2 (select+apply, R13-proven structure; ONE change: normal stores instead
// of nontemporal). Theory: nt-stores bypass the 256 MB Infinity Cache and
// stream synchronously to HBM (R7: 23 us for 100 MB vs fill's 7 TB/s).
// Normal stores write-allocate in L3 (in 96 + out 100 MB < 256 MB) and
// drain lazily after kernel end.
// 768 blocks x 256 thr = (row, 8-channel chunk). Distributed select:
// u[16]/thread (16 VGPR, no spill), binary search on uint bits, ping-pong
// LDS cross-wave sums, stable ties via wave scan + cross-wave prefix,
// 4096-bit mask in LDS, then stream: cached loads, bit-select, stores.
// ---------------------------------------------------------------------------
__global__ __launch_bounds__(256) void k_selapply(const float* __restrict__ i0,
                                                  const float* __restrict__ i1,
                                                  const float* __restrict__ i2,
                                                  const float* __restrict__ imp,
                                                  vf4* __restrict__ out) {
  __shared__ unsigned short mhalf[256];        // 4096-bit row mask
  __shared__ unsigned smn[4], smx[4];
  __shared__ int scnt[2][4];                   // ping-pong per-wave counts
  __shared__ int sgt[4], seq_[4];
  const int blk  = blockIdx.x;
  const int row  = blk >> 5;                   // 0..23 (t*8+b)
  const int cb   = blk & 31;                   // 8-channel chunk within row
  const int tid  = threadIdx.x;
  const int lane = tid & 63;
  const int wv   = tid >> 6;

  // ---- load this thread's 16 consecutive imp values (4 x vf4) ------------
  unsigned u[16];
  {
    const vf4* p = reinterpret_cast<const vf4*>(imp + (size_t)row * HW) + tid * 4;
#pragma unroll
    for (int j = 0; j < 4; ++j) {
      vf4 v = p[j];
      u[4 * j + 0] = __float_as_uint(v.x);
      u[4 * j + 1] = __float_as_uint(v.y);
      u[4 * j + 2] = __float_as_uint(v.z);
      u[4 * j + 3] = __float_as_uint(v.w);
    }
  }

  // ---- block min/max prescan ----------------------------------------------
  unsigned mx = 0u, mn = 0xFFFFFFFFu;
#pragma unroll
  for (int j = 0; j < 16; ++j) {
    mx = (u[j] > mx) ? u[j] : mx;
    mn = (u[j] < mn) ? u[j] : mn;
  }
#pragma unroll
  for (int off = 32; off > 0; off >>= 1) {
    unsigned ox = (unsigned)__shfl_xor((int)mx, off, 64);
    unsigned on = (unsigned)__shfl_xor((int)mn, off, 64);
    mx = (ox > mx) ? ox : mx;
    mn = (on < mn) ? on : mn;
  }
  if (lane == 0) { smn[wv] = mn; smx[wv] = mx; }
  __syncthreads();
#pragma unroll
  for (int w = 0; w < 4; ++w) {
    mn = (smn[w] < mn) ? smn[w] : mn;
    mx = (smx[w] > mx) ? smx[w] : mx;
  }

  // ---- binary search k-th largest on uint bits (uniform trip count) ------
  unsigned lo = mn, hi = mx + 1u;              // cnt_ge(lo)>=K, cnt_ge(hi)<K
  int pp = 0;
  while (hi - lo > 1u) {
    unsigned mid = lo + ((hi - lo) >> 1);
    int c = 0;
#pragma unroll
    for (int j = 0; j < 16; ++j) c += (u[j] >= mid);
#pragma unroll
    for (int off = 32; off > 0; off >>= 1) c += __shfl_xor(c, off, 64);
    if (lane == 0) scnt[pp][wv] = c;
    __syncthreads();                           // ping-pong: 1 barrier/iter
    c = scnt[pp][0] + scnt[pp][1] + scnt[pp][2] + scnt[pp][3];  // uniform
    pp ^= 1;
    if (c >= TOPK) lo = mid; else hi = mid;
  }
  const unsigned thr = lo;

  // ---- counts + stable tie-rank (thread order == index order) ------------
  int eq = 0, gt = 0;
#pragma unroll
  for (int j = 0; j < 16; ++j) {
    eq += (u[j] == thr);
    gt += (u[j] > thr);
  }
  int g = gt;
#pragma unroll
  for (int off = 32; off > 0; off >>= 1) g += __shfl_xor(g, off, 64);
  int incl = eq;                               // wave-inclusive scan of eq
#pragma unroll
  for (int off = 1; off < 64; off <<= 1) {
    int n = __shfl_up(incl, off, 64);
    if (lane >= off) incl += n;
  }
  if (lane == 0) sgt[wv] = g;
  if (lane == 63) seq_[wv] = incl;
  __syncthreads();
  const int g_tot = sgt[0] + sgt[1] + sgt[2] + sgt[3];
  int eqbase = 0;
#pragma unroll
  for (int w = 0; w < 4; ++w) eqbase += (w < wv) ? seq_[w] : 0;
  int r = eqbase + incl - eq;                  // exclusive prefix, this thread
  const int needed = TOPK - g_tot;             // >=1 by search invariant

  // ---- emit 16-bit mask slice ---------------------------------------------
  unsigned bits = 0u;
#pragma unroll
  for (int s = 0; s < 16; ++s) {
    unsigned x = u[s];
    int e = (x == thr);
    unsigned keep = (x > thr || (e && r < needed)) ? 1u : 0u;
    bits |= keep << s;
    r += e;
  }
  mhalf[tid] = (unsigned short)bits;
  __syncthreads();

  // ---- apply: 8 channels of this row, 32 vf4/thread, 8 batches of 4 ------
  const int t = row >> 3;
  const vf4* src = (t == 0 ? (const vf4*)i0 : (t == 1 ? (const vf4*)i1 : (const vf4*)i2));
  const size_t src_base = ((size_t)(row & 7) * NC + (size_t)cb * CHB) * (HW / 4);
  vf4* obase = out + (size_t)row * NC * (HW / 4) + (size_t)cb * CHB * (HW / 4);
#pragma unroll
  for (int it = 0; it < VPT / 4; ++it) {
    int jj[4];
    vf4 a[4];
    unsigned nib[4];
#pragma unroll
    for (int q = 0; q < 4; ++q) {
      int j = tid + (it * 4 + q) * 256;        // 0..8191 vf4 within chunk
      jj[q] = j;
      a[q] = src[src_base + j];                // cached read (L3-resident)
      int h4 = j & 1023;                       // vf4 col within row
      nib[q] = ((unsigned)mhalf[h4 >> 2] >> ((h4 & 3) * 4)) & 15u;
    }
#pragma unroll
    for (int q = 0; q < 4; ++q) {
      vf4 rr;
      rr.x = (nib[q] & 1u) ? a[q].x : 0.f;
      rr.y = (nib[q] & 2u) ? a[q].y : 0.f;
      rr.z = (nib[q] & 4u) ? a[q].z : 0.f;
      rr.w = (nib[q] & 8u) ? a[q].w : 0.f;
      obase[jj[q]] = rr;                       // NORMAL store (L3 write-allocate)
    }
  }
}

extern "C" void kernel_launch(void* const* d_in, const int* in_sizes, int n_in,
                              void* d_out, int out_size, void* d_ws, size_t ws_size,
                              hipStream_t stream) {
  const float* i0 = (const float*)d_in[0];
  const float* i1 = (const float*)d_in[1];
  const float* i2 = (const float*)d_in[2];
  float* imp = (float*)d_ws;   // 384 KB scratch (imp only; mask stays on-chip)

  k_imp<<<384, 256, 0, stream>>>(i0, i1, i2, imp);
  k_selapply<<<K2B, 256, 0, stream>>>(i0, i1, i2, imp, (vf4*)d_out);
}